// Round 7
// baseline (91.859 us; speedup 1.0000x reference)
//
#include <hip/hip_runtime.h>
#include <math.h>

#define PH 7
#define PW 7
#define B_ 4
#define C_ 256
#define H_ 50
#define W_ 50
#define R_ 256
#define S_ (H_ * W_)     // 2500
#define NCELL (PH * PW)  // 49
#define MAXW 9           // max window width: ceil(50/7)+1
#define OUTR (C_ * NCELL)  // 12544 floats per roi

// ---------- kernel 1: features (B,C,H,W) -> (B,H,W,C) ----------
__global__ void transpose_chw_hwc(const float* __restrict__ in, float* __restrict__ out) {
    __shared__ float tile[32][33];
    const int b  = blockIdx.z;
    const int s0 = blockIdx.x * 32;
    const int c0 = blockIdx.y * 32;
    const float* inb  = in  + (size_t)b * C_ * S_;
    float*       outb = out + (size_t)b * S_ * C_;
    const int tx = threadIdx.x;
    #pragma unroll
    for (int i = threadIdx.y; i < 32; i += 8) {
        const int s = s0 + tx;
        if (s < S_) tile[i][tx] = inb[(size_t)(c0 + i) * S_ + s];
    }
    __syncthreads();
    #pragma unroll
    for (int i = threadIdx.y; i < 32; i += 8) {
        const int s = s0 + i;
        if (s < S_) outb[(size_t)s * C_ + (c0 + tx)] = tile[tx][i];
    }
}

__device__ __forceinline__ float4 max4(float4 a, float4 b) {
    a.x = fmaxf(a.x, b.x); a.y = fmaxf(a.y, b.y);
    a.z = fmaxf(a.z, b.z); a.w = fmaxf(a.w, b.w);
    return a;
}

// ---------- kernel 2: fused pool + output layout ----------
// One block (512 thr = 8 waves) per roi. Waves stripe the 49 cells; per cell
// each wave covers all 256 channels (lane owns 4 via float4) with 2-row x kw
// guarded load batches (wave-uniform branch, 18 loads in flight).
// Results land in a FLAT c-major LDS image of out[r] (obuf[c*49+cell]);
// the epilogue is a straight contiguous 50 KB LDS->global float4 copy:
// conflict-free LDS reads, fully-coalesced full-line stores, zero write
// amplification, no tmp round-trip, one fewer dispatch than round 6.
__global__ void __launch_bounds__(512)
roi_pool_fused(const float* __restrict__ ft, const int* __restrict__ rois,
               float* __restrict__ out) {
    __shared__ float obuf[OUTR];     // 50176 B

    const int r    = blockIdx.x;
    const int t    = threadIdx.x;
    const int wave = t >> 6;
    const int lane = t & 63;

    const int* roi = rois + r * 5;
    const int b  = roi[0];
    const int x1 = roi[1] >> 4;   // floor(v/16), v >= 0
    const int y1 = roi[2] >> 4;
    const int x2 = roi[3] >> 4;
    const int y2 = roi[4] >> 4;
    const int h = y2 - y1 + 1;
    const int w = x2 - x1 + 1;

    const float* fb = ft + (size_t)b * S_ * C_ + 4 * lane;

    for (int cell = wave; cell < NCELL; cell += 8) {
        const int ph = cell / PW;
        const int pw = cell - ph * PW;
        const int sh = y1 + (ph * h) / PH;
        const int eh = y1 + ((ph + 1) * h + PH - 1) / PH;
        const int sw = x1 + (pw * w) / PW;
        const int ew = x1 + ((pw + 1) * w + PW - 1) / PW;
        const int kw = ew - sw;      // 1..9, wave-uniform

        float4 acc = make_float4(-INFINITY, -INFINITY, -INFINITY, -INFINITY);
        for (int y = sh; y < eh; y += 2) {
            const int yb = (y + 1 < eh) ? (y + 1) : y;   // dup row, max-safe
            const float* p0 = fb + (size_t)(y  * W_ + sw) * C_;
            const float* p1 = fb + (size_t)(yb * W_ + sw) * C_;
            float4 v0[MAXW], v1[MAXW];
            #pragma unroll
            for (int k = 0; k < MAXW; ++k) {
                if (k < kw) {                            // wave-uniform branch
                    v0[k] = *(const float4*)(p0 + (size_t)k * C_);
                    v1[k] = *(const float4*)(p1 + (size_t)k * C_);
                }
            }
            #pragma unroll
            for (int k = 0; k < MAXW; ++k) {
                if (k < kw) acc = max4(acc, max4(v0[k], v1[k]));
            }
        }

        // flat c-major: obuf[c*49+cell]; 4 scalar stores, stride-196B
        // (8-way bank conflicts on 4 ops/cell — negligible)
        const int c = 4 * lane;
        obuf[(c + 0) * NCELL + cell] = acc.x;
        obuf[(c + 1) * NCELL + cell] = acc.y;
        obuf[(c + 2) * NCELL + cell] = acc.z;
        obuf[(c + 3) * NCELL + cell] = acc.w;
    }

    __syncthreads();

    // contiguous 50 KB copy: LDS float4 (conflict-free) -> global float4
    const float4* src4 = (const float4*)obuf;
    float4* dst4 = (float4*)(out + (size_t)r * OUTR);
    #pragma unroll
    for (int fi = t; fi < OUTR / 4; fi += 512) {
        dst4[fi] = src4[fi];
    }
}

extern "C" void kernel_launch(void* const* d_in, const int* in_sizes, int n_in,
                              void* d_out, int out_size, void* d_ws, size_t ws_size,
                              hipStream_t stream) {
    const float* features = (const float*)d_in[0];
    const int*   rois     = (const int*)d_in[1];
    float*       out      = (float*)d_out;

    float* ft = (float*)d_ws;  // 10.24 MB scratch
    dim3 tgrid((S_ + 31) / 32, C_ / 32, B_);
    transpose_chw_hwc<<<tgrid, dim3(32, 8), 0, stream>>>(features, ft);
    roi_pool_fused<<<R_, 512, 0, stream>>>(ft, rois, out);
}